// Round 3
// baseline (120.049 us; speedup 1.0000x reference)
//
#include <hip/hip_runtime.h>
#include <math.h>

#define B   8
#define NL  256
#define NP  16384
#define DL  10
#define DP  4

#define DELTA  0.01f
// EPS = A_C = B_C = 1.0, L_BIND = 1.0, L_MREG = 0.1

#define NBIND 2048
#define NMSE  8
#define NBLK  (NBIND + NMSE)

typedef float v2f __attribute__((ext_vector_type(2)));

// ---- 1-ulp HW transcendentals (guarded fallbacks) ----
static __device__ __forceinline__ float fast_sqrtf(float x) {
#if __has_builtin(__builtin_amdgcn_sqrtf)
    return __builtin_amdgcn_sqrtf(x);   // v_sqrt_f32
#else
    return sqrtf(x);
#endif
}
static __device__ __forceinline__ float fast_rcpf(float x) {
#if __has_builtin(__builtin_amdgcn_rcpf)
    return __builtin_amdgcn_rcpf(x);    // v_rcp_f32
#else
    return 1.0f / x;
#endif
}

// ws layout:
//   [0]      unsigned counter   (zeroed by a 4-byte memset node each call)
//   [16..]   partials: 2*NBIND doubles {elec,vdw} then NMSE*3 {de,mr,ms}
//
// Single fused kernel:
//   blocks [0,NBIND): binding energy, blk -> b(8) x pchunk(64) x lchunk(4)
//     - 64 ligand atoms staged SoA in LDS (coords + argmax charge)
//     - inner loop processes 2 atoms/iter as float2 -> v_pk_* packed fp32
//   blocks [NBIND,NBLK): masked MSE / mreg / mask-sum partials
//   Last block to finish (device-scope counter) reduces all partials and
//   writes the scalar loss. Deterministic: fixed-order fp64 reduction.
__global__ __launch_bounds__(256) void fused_kernel(
    const float* __restrict__ prot_coords,   // (B,NP,3)
    const float* __restrict__ prot_feat,     // (B,NP,DP)
    const float* __restrict__ tc2,           // (B,NL,3)
    const float* __restrict__ lig_feat,      // (B,NL,DL)
    const float* __restrict__ lig_tab,       // (DL)
    const float* __restrict__ prot_tab,      // (DP)
    const float* __restrict__ pred_noise,    // (B,NL,3)
    const float* __restrict__ tgt_coords,    // (B,NL,3)
    const float* __restrict__ scaf_coords,   // (B,NL,3)
    const float* __restrict__ mask,          // (B,NL)
    unsigned*    __restrict__ counter,
    double*      __restrict__ partials,
    float*       __restrict__ out)
{
    const int tid = threadIdx.x;
    const int blk = blockIdx.x;
    const int lane = tid & 63, w = tid >> 6;

    __shared__ double sred[4][3];

    if (blk < NBIND) {
        // ---------------- binding energy ----------------
        const int lchunk = blk & 3;
        const int pchunk = (blk >> 2) & 63;
        const int b      = blk >> 8;

        // SoA ligand staging: v2f loads in the loop are plain ds_read_b64
        __shared__ float sx[64], sy[64], sz[64], sw[64];
        if (tid < 64) {
            const int li = b * NL + lchunk * 64 + tid;
            const float* f = lig_feat + (size_t)li * DL;
            float best = f[0]; float q = lig_tab[0];
            #pragma unroll
            for (int j = 1; j < DL; ++j) {
                float v = f[j];
                float t = lig_tab[j];            // uniform -> s_load
                if (v > best) { best = v; q = t; }
            }
            const float* c = tc2 + (size_t)li * 3;
            sx[tid] = c[0]; sy[tid] = c[1]; sz[tid] = c[2]; sw[tid] = q;
        }

        // protein atom for this thread (overlaps staging)
        const int m = b * NP + pchunk * 256 + tid;
        const float* pc = prot_coords + (size_t)m * 3;
        const float px = pc[0], py = pc[1], pz = pc[2];
        const float4 pf = reinterpret_cast<const float4*>(prot_feat)[m];
        float qb = pf.x, qp = prot_tab[0];
        { float t = prot_tab[1]; if (pf.y > qb) { qb = pf.y; qp = t; } }
        { float t = prot_tab[2]; if (pf.z > qb) { qb = pf.z; qp = t; } }
        { float t = prot_tab[3]; if (pf.w > qb) { qb = pf.w; qp = t; } }

        __syncthreads();

        v2f eacc = {0.0f, 0.0f}, vacc = {0.0f, 0.0f};
        #pragma unroll 8
        for (int j = 0; j < 64; j += 2) {
            v2f lx = *(const v2f*)&sx[j];        // ds_read_b64 broadcast
            v2f ly = *(const v2f*)&sy[j];
            v2f lz = *(const v2f*)&sz[j];
            v2f lw = *(const v2f*)&sw[j];
            v2f dx = lx - px;
            v2f dy = ly - py;
            v2f dz = lz - pz;
            v2f d2 = __builtin_elementwise_fma(dx, dx,
                     __builtin_elementwise_fma(dy, dy, dz * dz));
            v2f d;
            d.x = fast_sqrtf(d2.x);
            d.y = fast_sqrtf(d2.y);
            d += DELTA;
            v2f inv;
            inv.x = fast_rcpf(d.x);
            inv.y = fast_rcpf(d.y);
            v2f inv2 = inv * inv;
            v2f inv6 = inv2 * inv2 * inv2;
            eacc = __builtin_elementwise_fma(lw, inv, eacc);      // ql*inv
            vacc = __builtin_elementwise_fma(inv6, inv6 - 1.0f, vacc);
        }

        double e = (double)(qp * (eacc.x + eacc.y));
        double v = (double)(vacc.x + vacc.y);
        #pragma unroll
        for (int off = 32; off > 0; off >>= 1) {
            e += __shfl_down(e, off, 64);
            v += __shfl_down(v, off, 64);
        }
        if (lane == 0) { sred[w][0] = e; sred[w][1] = v; }
        __syncthreads();
        if (tid == 0) {
            double pe = sred[0][0] + sred[1][0] + sred[2][0] + sred[3][0];
            double pv = sred[0][1] + sred[1][1] + sred[2][1] + sred[3][1];
            __hip_atomic_store(&partials[2*blk],   pe, __ATOMIC_RELAXED, __HIP_MEMORY_SCOPE_AGENT);
            __hip_atomic_store(&partials[2*blk+1], pv, __ATOMIC_RELAXED, __HIP_MEMORY_SCOPE_AGENT);
        }
    } else {
        // ---------------- masked MSE / mreg partials ----------------
        const int idx = blk - NBIND;             // [0,8)
        const int i   = idx * 256 + tid;         // [0, B*NL)
        float mk = mask[i];
        float a0 = pred_noise[3*i+0] - tgt_coords[3*i+0];
        float a1 = pred_noise[3*i+1] - tgt_coords[3*i+1];
        float a2 = pred_noise[3*i+2] - tgt_coords[3*i+2];
        double de = (double)mk * ((double)a0*a0 + (double)a1*a1 + (double)a2*a2);
        float s0 = scaf_coords[3*i+0] - tgt_coords[3*i+0];
        float s1 = scaf_coords[3*i+1] - tgt_coords[3*i+1];
        float s2 = scaf_coords[3*i+2] - tgt_coords[3*i+2];
        double mr = (double)mk * ((double)s0*s0 + (double)s1*s1 + (double)s2*s2);
        double ms = (double)mk;
        #pragma unroll
        for (int off = 32; off > 0; off >>= 1) {
            de += __shfl_down(de, off, 64);
            mr += __shfl_down(mr, off, 64);
            ms += __shfl_down(ms, off, 64);
        }
        if (lane == 0) { sred[w][0] = de; sred[w][1] = mr; sred[w][2] = ms; }
        __syncthreads();
        if (tid == 0) {
            double pd = sred[0][0] + sred[1][0] + sred[2][0] + sred[3][0];
            double pm = sred[0][1] + sred[1][1] + sred[2][1] + sred[3][1];
            double pq = sred[0][2] + sred[1][2] + sred[2][2] + sred[3][2];
            __hip_atomic_store(&partials[2*NBIND + idx*3 + 0], pd, __ATOMIC_RELAXED, __HIP_MEMORY_SCOPE_AGENT);
            __hip_atomic_store(&partials[2*NBIND + idx*3 + 1], pm, __ATOMIC_RELAXED, __HIP_MEMORY_SCOPE_AGENT);
            __hip_atomic_store(&partials[2*NBIND + idx*3 + 2], pq, __ATOMIC_RELAXED, __HIP_MEMORY_SCOPE_AGENT);
        }
    }

    // ------------- last-block final reduction -------------
    __shared__ unsigned sOld;
    if (tid == 0) {
        // release: orders the partial stores above before the increment
        sOld = __hip_atomic_fetch_add(counter, 1u, __ATOMIC_ACQ_REL, __HIP_MEMORY_SCOPE_AGENT);
    }
    __syncthreads();
    if (sOld == NBLK - 1) {
        // acquire side: the acq_rel RMW on tid 0 synchronized with all
        // releases; agent-scope relaxed loads below bypass stale caches.
        double el = 0.0, vd = 0.0;
        for (int i = tid; i < NBIND; i += 256) {
            el += __hip_atomic_load(&partials[2*i],   __ATOMIC_RELAXED, __HIP_MEMORY_SCOPE_AGENT);
            vd += __hip_atomic_load(&partials[2*i+1], __ATOMIC_RELAXED, __HIP_MEMORY_SCOPE_AGENT);
        }
        double de = 0.0, mr = 0.0, ms = 0.0;
        if (tid < NMSE) {
            de = __hip_atomic_load(&partials[2*NBIND + tid*3 + 0], __ATOMIC_RELAXED, __HIP_MEMORY_SCOPE_AGENT);
            mr = __hip_atomic_load(&partials[2*NBIND + tid*3 + 1], __ATOMIC_RELAXED, __HIP_MEMORY_SCOPE_AGENT);
            ms = __hip_atomic_load(&partials[2*NBIND + tid*3 + 2], __ATOMIC_RELAXED, __HIP_MEMORY_SCOPE_AGENT);
        }
        #pragma unroll
        for (int off = 32; off > 0; off >>= 1) {
            el += __shfl_down(el, off, 64);
            vd += __shfl_down(vd, off, 64);
            de += __shfl_down(de, off, 64);
            mr += __shfl_down(mr, off, 64);
            ms += __shfl_down(ms, off, 64);
        }
        __shared__ double sf[4][5];
        if (lane == 0) { sf[w][0]=el; sf[w][1]=vd; sf[w][2]=de; sf[w][3]=mr; sf[w][4]=ms; }
        __syncthreads();
        if (tid == 0) {
            el = sf[0][0]+sf[1][0]+sf[2][0]+sf[3][0];
            vd = sf[0][1]+sf[1][1]+sf[2][1]+sf[3][1];
            de = sf[0][2]+sf[1][2]+sf[2][2]+sf[3][2];
            mr = sf[0][3]+sf[1][3]+sf[2][3]+sf[3][3];
            ms = sf[0][4]+sf[1][4]+sf[2][4]+sf[3][4];
            double loss_bind = (el + vd) / (double)B;
            double loss = de / ms + loss_bind + 0.1 * (mr / ms);
            out[0] = (float)loss;
        }
    }
}

// ---------------------------------------------------------------------------
extern "C" void kernel_launch(void* const* d_in, const int* in_sizes, int n_in,
                              void* d_out, int out_size, void* d_ws, size_t ws_size,
                              hipStream_t stream)
{
    const float* pred_noise  = (const float*)d_in[0];
    const float* tgt_coords  = (const float*)d_in[1];
    const float* scaf_coords = (const float*)d_in[2];
    const float* tc2         = (const float*)d_in[3];
    const float* lig_feat    = (const float*)d_in[4];
    const float* mask        = (const float*)d_in[5];
    const float* prot_coords = (const float*)d_in[6];
    const float* prot_feat   = (const float*)d_in[7];
    const float* lig_tab     = (const float*)d_in[8];
    const float* prot_tab    = (const float*)d_in[9];
    float* out = (float*)d_out;

    unsigned* counter = (unsigned*)d_ws;                 // 4 B (zeroed below)
    double*   partials = (double*)((char*)d_ws + 16);    // 2*2048+24 doubles

    hipMemsetAsync(counter, 0, sizeof(unsigned), stream);   // graph memset node
    fused_kernel<<<NBLK, 256, 0, stream>>>(
        prot_coords, prot_feat, tc2, lig_feat, lig_tab, prot_tab,
        pred_noise, tgt_coords, scaf_coords, mask, counter, partials, out);
}

// Round 4
// 91.406 us; speedup vs baseline: 1.3134x; 1.3134x over previous
//
#include <hip/hip_runtime.h>
#include <math.h>

#define B   8
#define NL  256
#define NP  16384
#define DL  10
#define DP  4

#define DELTA  0.01f
// EPS = A_C = B_C = 1.0, L_BIND = 1.0, L_MREG = 0.1

#define NBINDBLK 1024     // b(8) x pchunk(64) x lhalf(2)
#define NMSE     8
#define LATOMS   128      // ligand atoms handled per binding block

typedef float v4f __attribute__((ext_vector_type(4)));

// ---- 1-ulp HW transcendentals (guarded fallbacks) ----
static __device__ __forceinline__ float fast_sqrtf(float x) {
#if __has_builtin(__builtin_amdgcn_sqrtf)
    return __builtin_amdgcn_sqrtf(x);   // v_sqrt_f32
#else
    return sqrtf(x);
#endif
}
static __device__ __forceinline__ float fast_rcpf(float x) {
#if __has_builtin(__builtin_amdgcn_rcpf)
    return __builtin_amdgcn_rcpf(x);    // v_rcp_f32
#else
    return 1.0f / x;
#endif
}

// ---------------------------------------------------------------------------
// Kernel 1: binding-energy + MSE partials. TWO-KERNEL STRUCTURE (no global
// atomics — R3's 2048-deep same-address acq_rel burst serialized at one L2
// line and cost +25 us; kernel-boundary ordering is free).
//   blocks [0,1024): binding. blk -> b(8) x pchunk(64) x lhalf(2).
//     - 128 ligand atoms staged ONCE via coalesced LDS bounce (coords+feats),
//       argmax charge computed from LDS.
//     - thread owns protein atom pchunk*256+tid; 128-iter loop, float4
//       ext-vector math (v_pk_* pairs), ds_read_b128 SoA broadcasts,
//       unroll 4 for cross-iteration LDS prefetch (VGPR budget ~100).
//   blocks [1024,1032): masked MSE / mreg / mask-sum partials.
//   Deterministic fixed-order fp64 block reductions -> partials.
// ---------------------------------------------------------------------------
__global__ __launch_bounds__(256) void pair_mse_kernel(
    const float* __restrict__ prot_coords,   // (B,NP,3)
    const float* __restrict__ prot_feat,     // (B,NP,DP)
    const float* __restrict__ tc2,           // (B,NL,3)
    const float* __restrict__ lig_feat,      // (B,NL,DL)
    const float* __restrict__ lig_tab,       // (DL)
    const float* __restrict__ prot_tab,      // (DP)
    const float* __restrict__ pred_noise,    // (B,NL,3)
    const float* __restrict__ tgt_coords,    // (B,NL,3)
    const float* __restrict__ scaf_coords,   // (B,NL,3)
    const float* __restrict__ mask,          // (B,NL)
    double*      __restrict__ partials)
{
    const int tid  = threadIdx.x;
    const int blk  = blockIdx.x;
    const int lane = tid & 63, w = tid >> 6;

    __shared__ double sred[4][3];

    if (blk < NBINDBLK) {
        // ---------------- binding energy ----------------
        const int lhalf  = blk & 1;
        const int pchunk = (blk >> 1) & 63;
        const int b      = blk >> 7;

        __shared__ __align__(16) float sx[LATOMS], sy[LATOMS], sz[LATOMS], sw[LATOMS];
        __shared__ float sc[LATOMS * 3];      // coord bounce
        __shared__ float sfeat[LATOMS * DL];  // feature bounce

        const int abase = b * NL + lhalf * LATOMS;

        // fully-coalesced staging (all 256 threads)
        {
            const float* csrc = tc2 + (size_t)abase * 3;
            #pragma unroll
            for (int t = tid; t < LATOMS * 3; t += 256) sc[t] = csrc[t];
            const float* fsrc = lig_feat + (size_t)abase * DL;
            #pragma unroll
            for (int t = tid; t < LATOMS * DL; t += 256) sfeat[t] = fsrc[t];
        }

        // protein atom for this thread (overlaps staging)
        const int m = b * NP + pchunk * 256 + tid;
        const float* pc = prot_coords + (size_t)m * 3;
        const float px = pc[0], py = pc[1], pz = pc[2];
        const float4 pf = reinterpret_cast<const float4*>(prot_feat)[m];
        float qb = pf.x, qp = prot_tab[0];
        { float t = prot_tab[1]; if (pf.y > qb) { qb = pf.y; qp = t; } }
        { float t = prot_tab[2]; if (pf.z > qb) { qb = pf.z; qp = t; } }
        { float t = prot_tab[3]; if (pf.w > qb) { qb = pf.w; qp = t; } }

        __syncthreads();

        // SoA build + ligand argmax from LDS (first 2 waves)
        if (tid < LATOMS) {
            float best = sfeat[tid * DL];
            float q = lig_tab[0];
            #pragma unroll
            for (int j = 1; j < DL; ++j) {
                float v = sfeat[tid * DL + j];
                float t = lig_tab[j];            // uniform -> s_load
                if (v > best) { best = v; q = t; }
            }
            sx[tid] = sc[tid * 3 + 0];
            sy[tid] = sc[tid * 3 + 1];
            sz[tid] = sc[tid * 3 + 2];
            sw[tid] = q;
        }
        __syncthreads();

        v4f eacc = {0.f, 0.f, 0.f, 0.f}, vacc = {0.f, 0.f, 0.f, 0.f};
        #pragma unroll 4
        for (int j = 0; j < LATOMS; j += 4) {
            v4f lx = *(const v4f*)&sx[j];        // ds_read_b128 broadcast
            v4f ly = *(const v4f*)&sy[j];
            v4f lz = *(const v4f*)&sz[j];
            v4f lw = *(const v4f*)&sw[j];
            v4f dx = lx - px;
            v4f dy = ly - py;
            v4f dz = lz - pz;
            v4f d2 = __builtin_elementwise_fma(dx, dx,
                     __builtin_elementwise_fma(dy, dy, dz * dz));
            v4f d;
            d.x = fast_sqrtf(d2.x); d.y = fast_sqrtf(d2.y);
            d.z = fast_sqrtf(d2.z); d.w = fast_sqrtf(d2.w);
            d += DELTA;
            v4f inv;
            inv.x = fast_rcpf(d.x); inv.y = fast_rcpf(d.y);
            inv.z = fast_rcpf(d.z); inv.w = fast_rcpf(d.w);
            v4f inv2 = inv * inv;
            v4f inv6 = inv2 * inv2 * inv2;
            eacc = __builtin_elementwise_fma(lw, inv, eacc);      // ql*inv
            vacc = __builtin_elementwise_fma(inv6, inv6 - 1.0f, vacc);
        }

        double e = (double)(qp * ((eacc.x + eacc.y) + (eacc.z + eacc.w)));
        double v = (double)((vacc.x + vacc.y) + (vacc.z + vacc.w));
        #pragma unroll
        for (int off = 32; off > 0; off >>= 1) {
            e += __shfl_down(e, off, 64);
            v += __shfl_down(v, off, 64);
        }
        if (lane == 0) { sred[w][0] = e; sred[w][1] = v; }
        __syncthreads();
        if (tid == 0) {
            partials[2 * blk]     = sred[0][0] + sred[1][0] + sred[2][0] + sred[3][0];
            partials[2 * blk + 1] = sred[0][1] + sred[1][1] + sred[2][1] + sred[3][1];
        }
    } else {
        // ---------------- masked MSE / mreg partials ----------------
        const int idx = blk - NBINDBLK;          // [0,8)
        const int i   = idx * 256 + tid;         // [0, B*NL)
        float mk = mask[i];
        float a0 = pred_noise[3*i+0] - tgt_coords[3*i+0];
        float a1 = pred_noise[3*i+1] - tgt_coords[3*i+1];
        float a2 = pred_noise[3*i+2] - tgt_coords[3*i+2];
        double de = (double)mk * ((double)a0*a0 + (double)a1*a1 + (double)a2*a2);
        float s0 = scaf_coords[3*i+0] - tgt_coords[3*i+0];
        float s1 = scaf_coords[3*i+1] - tgt_coords[3*i+1];
        float s2 = scaf_coords[3*i+2] - tgt_coords[3*i+2];
        double mr = (double)mk * ((double)s0*s0 + (double)s1*s1 + (double)s2*s2);
        double ms = (double)mk;
        #pragma unroll
        for (int off = 32; off > 0; off >>= 1) {
            de += __shfl_down(de, off, 64);
            mr += __shfl_down(mr, off, 64);
            ms += __shfl_down(ms, off, 64);
        }
        if (lane == 0) { sred[w][0] = de; sred[w][1] = mr; sred[w][2] = ms; }
        __syncthreads();
        if (tid == 0) {
            partials[2*NBINDBLK + idx*3 + 0] = sred[0][0]+sred[1][0]+sred[2][0]+sred[3][0];
            partials[2*NBINDBLK + idx*3 + 1] = sred[0][1]+sred[1][1]+sred[2][1]+sred[3][1];
            partials[2*NBINDBLK + idx*3 + 2] = sred[0][2]+sred[1][2]+sred[2][2]+sred[3][2];
        }
    }
}

// ---------------------------------------------------------------------------
// Kernel 2: finalize — reduce all partials, write scalar loss.
// ---------------------------------------------------------------------------
__global__ __launch_bounds__(256) void finalize_kernel(
    const double* __restrict__ partials,
    float* __restrict__ out)
{
    const int tid = threadIdx.x;
    const int lane = tid & 63, w = tid >> 6;
    double el = 0.0, vd = 0.0;
    for (int i = tid; i < NBINDBLK; i += 256) {
        el += partials[2*i];
        vd += partials[2*i + 1];
    }
    double de = 0.0, mr = 0.0, ms = 0.0;
    if (tid < NMSE) {
        de = partials[2*NBINDBLK + tid*3 + 0];
        mr = partials[2*NBINDBLK + tid*3 + 1];
        ms = partials[2*NBINDBLK + tid*3 + 2];
    }
    #pragma unroll
    for (int off = 32; off > 0; off >>= 1) {
        el += __shfl_down(el, off, 64);
        vd += __shfl_down(vd, off, 64);
        de += __shfl_down(de, off, 64);
        mr += __shfl_down(mr, off, 64);
        ms += __shfl_down(ms, off, 64);
    }
    __shared__ double s[4][5];
    if (lane == 0) { s[w][0]=el; s[w][1]=vd; s[w][2]=de; s[w][3]=mr; s[w][4]=ms; }
    __syncthreads();
    if (tid == 0) {
        el = s[0][0]+s[1][0]+s[2][0]+s[3][0];
        vd = s[0][1]+s[1][1]+s[2][1]+s[3][1];
        de = s[0][2]+s[1][2]+s[2][2]+s[3][2];
        mr = s[0][3]+s[1][3]+s[2][3]+s[3][3];
        ms = s[0][4]+s[1][4]+s[2][4]+s[3][4];
        double loss_bind = (el + vd) / (double)B;
        double loss = de / ms + loss_bind + 0.1 * (mr / ms);
        out[0] = (float)loss;
    }
}

// ---------------------------------------------------------------------------
extern "C" void kernel_launch(void* const* d_in, const int* in_sizes, int n_in,
                              void* d_out, int out_size, void* d_ws, size_t ws_size,
                              hipStream_t stream)
{
    const float* pred_noise  = (const float*)d_in[0];
    const float* tgt_coords  = (const float*)d_in[1];
    const float* scaf_coords = (const float*)d_in[2];
    const float* tc2         = (const float*)d_in[3];
    const float* lig_feat    = (const float*)d_in[4];
    const float* mask        = (const float*)d_in[5];
    const float* prot_coords = (const float*)d_in[6];
    const float* prot_feat   = (const float*)d_in[7];
    const float* lig_tab     = (const float*)d_in[8];
    const float* prot_tab    = (const float*)d_in[9];
    float* out = (float*)d_out;

    double* partials = (double*)d_ws;   // 2*1024 + 24 doubles = ~16.6 KB

    pair_mse_kernel<<<NBINDBLK + NMSE, 256, 0, stream>>>(
        prot_coords, prot_feat, tc2, lig_feat, lig_tab, prot_tab,
        pred_noise, tgt_coords, scaf_coords, mask, partials);
    finalize_kernel<<<1, 256, 0, stream>>>(partials, out);
}

// Round 5
// 90.426 us; speedup vs baseline: 1.3276x; 1.0108x over previous
//
#include <hip/hip_runtime.h>
#include <math.h>

#define B   8
#define NL  256
#define NP  16384
#define DL  10
#define DP  4

#define DELTA  0.01f
// EPS = A_C = B_C = 1.0, L_BIND = 1.0, L_MREG = 0.1

#define NBINDBLK 1024     // b(8) x pchunk(32: 512 proteins) x lquarter(4)
#define NMSE     8
#define LATOMS   64       // ligand atoms per binding block
#define PBLK     2        // protein atoms per thread (register blocking)

typedef float v4f __attribute__((ext_vector_type(4)));

// ---- 1-ulp HW transcendentals (guarded fallbacks) ----
static __device__ __forceinline__ float fast_sqrtf(float x) {
#if __has_builtin(__builtin_amdgcn_sqrtf)
    return __builtin_amdgcn_sqrtf(x);   // v_sqrt_f32
#else
    return sqrtf(x);
#endif
}
static __device__ __forceinline__ float fast_rcpf(float x) {
#if __has_builtin(__builtin_amdgcn_rcpf)
    return __builtin_amdgcn_rcpf(x);    // v_rcp_f32
#else
    return 1.0f / x;
#endif
}

// ---------------------------------------------------------------------------
// Kernel 1: binding-energy + MSE partials.
//   R4 post-mortem: P=1 structure is LDS-return-bus bound (~10.2 us chip-wide:
//   4 ds_read_b128 per 256 pairs; broadcast still writes 4 VGPRs x 64 lanes).
//   R5: P=2 protein atoms per thread -> each LDS chunk feeds 512 pairs,
//   LDS-pipe time halves (~5.1 us); trans pipe (3.4 us) co-dominant.
//   blocks [0,1024): binding. blk -> b(8) x pchunk(32) x lquarter(4).
//   blocks [1024,1032): masked MSE / mreg / mask-sum partials.
//   Deterministic fixed-order fp64 block reductions -> partials (no atomics;
//   R3 showed a 2k-deep same-address acq_rel burst costs +25 us).
// ---------------------------------------------------------------------------
__global__ __launch_bounds__(256, 4) void pair_mse_kernel(
    const float* __restrict__ prot_coords,   // (B,NP,3)
    const float* __restrict__ prot_feat,     // (B,NP,DP)
    const float* __restrict__ tc2,           // (B,NL,3)
    const float* __restrict__ lig_feat,      // (B,NL,DL)
    const float* __restrict__ lig_tab,       // (DL)
    const float* __restrict__ prot_tab,      // (DP)
    const float* __restrict__ pred_noise,    // (B,NL,3)
    const float* __restrict__ tgt_coords,    // (B,NL,3)
    const float* __restrict__ scaf_coords,   // (B,NL,3)
    const float* __restrict__ mask,          // (B,NL)
    double*      __restrict__ partials)
{
    const int tid  = threadIdx.x;
    const int blk  = blockIdx.x;
    const int lane = tid & 63, w = tid >> 6;

    __shared__ double sred[4][3];

    if (blk < NBINDBLK) {
        // ---------------- binding energy ----------------
        const int lquarter = blk & 3;
        const int pchunk   = (blk >> 2) & 31;
        const int b        = blk >> 7;

        __shared__ __align__(16) float sx[LATOMS], sy[LATOMS], sz[LATOMS], sw[LATOMS];
        __shared__ float sc[LATOMS * 3];      // coord bounce (192 floats)
        __shared__ float sfeat[LATOMS * DL];  // feature bounce (640 floats)

        const int abase = b * NL + lquarter * LATOMS;

        // fully-coalesced staging
        {
            const float* csrc = tc2 + (size_t)abase * 3;
            if (tid < LATOMS * 3) sc[tid] = csrc[tid];
            const float* fsrc = lig_feat + (size_t)abase * DL;
            #pragma unroll
            for (int t = tid; t < LATOMS * DL; t += 256) sfeat[t] = fsrc[t];
        }

        // two protein atoms for this thread (overlaps staging)
        const int m0 = b * NP + pchunk * 512 + tid;
        const int m1 = m0 + 256;
        const float* pc0 = prot_coords + (size_t)m0 * 3;
        const float* pc1 = prot_coords + (size_t)m1 * 3;
        const float px0 = pc0[0], py0 = pc0[1], pz0 = pc0[2];
        const float px1 = pc1[0], py1 = pc1[1], pz1 = pc1[2];
        const float4 pf0 = reinterpret_cast<const float4*>(prot_feat)[m0];
        const float4 pf1 = reinterpret_cast<const float4*>(prot_feat)[m1];
        float qb0 = pf0.x, qp0 = prot_tab[0];
        { float t = prot_tab[1]; if (pf0.y > qb0) { qb0 = pf0.y; qp0 = t; } }
        { float t = prot_tab[2]; if (pf0.z > qb0) { qb0 = pf0.z; qp0 = t; } }
        { float t = prot_tab[3]; if (pf0.w > qb0) { qb0 = pf0.w; qp0 = t; } }
        float qb1 = pf1.x, qp1 = prot_tab[0];
        { float t = prot_tab[1]; if (pf1.y > qb1) { qb1 = pf1.y; qp1 = t; } }
        { float t = prot_tab[2]; if (pf1.z > qb1) { qb1 = pf1.z; qp1 = t; } }
        { float t = prot_tab[3]; if (pf1.w > qb1) { qb1 = pf1.w; qp1 = t; } }

        __syncthreads();

        // SoA build + ligand argmax from LDS (first wave)
        if (tid < LATOMS) {
            float best = sfeat[tid * DL];
            float q = lig_tab[0];
            #pragma unroll
            for (int j = 1; j < DL; ++j) {
                float v = sfeat[tid * DL + j];
                float t = lig_tab[j];            // uniform -> s_load
                if (v > best) { best = v; q = t; }
            }
            sx[tid] = sc[tid * 3 + 0];
            sy[tid] = sc[tid * 3 + 1];
            sz[tid] = sc[tid * 3 + 2];
            sw[tid] = q;
        }
        __syncthreads();

        v4f e0 = {0.f,0.f,0.f,0.f}, v0 = {0.f,0.f,0.f,0.f};
        v4f e1 = {0.f,0.f,0.f,0.f}, v1 = {0.f,0.f,0.f,0.f};
        #pragma unroll 2
        for (int j = 0; j < LATOMS; j += 4) {
            v4f lx = *(const v4f*)&sx[j];        // ds_read_b128 broadcast
            v4f ly = *(const v4f*)&sy[j];
            v4f lz = *(const v4f*)&sz[j];
            v4f lw = *(const v4f*)&sw[j];
            // protein 0
            {
                v4f dx = lx - px0, dy = ly - py0, dz = lz - pz0;
                v4f d2 = __builtin_elementwise_fma(dx, dx,
                         __builtin_elementwise_fma(dy, dy, dz * dz));
                v4f d;
                d.x = fast_sqrtf(d2.x); d.y = fast_sqrtf(d2.y);
                d.z = fast_sqrtf(d2.z); d.w = fast_sqrtf(d2.w);
                d += DELTA;
                v4f inv;
                inv.x = fast_rcpf(d.x); inv.y = fast_rcpf(d.y);
                inv.z = fast_rcpf(d.z); inv.w = fast_rcpf(d.w);
                v4f inv2 = inv * inv;
                v4f inv6 = inv2 * inv2 * inv2;
                e0 = __builtin_elementwise_fma(lw, inv, e0);
                v0 = __builtin_elementwise_fma(inv6, inv6 - 1.0f, v0);
            }
            // protein 1
            {
                v4f dx = lx - px1, dy = ly - py1, dz = lz - pz1;
                v4f d2 = __builtin_elementwise_fma(dx, dx,
                         __builtin_elementwise_fma(dy, dy, dz * dz));
                v4f d;
                d.x = fast_sqrtf(d2.x); d.y = fast_sqrtf(d2.y);
                d.z = fast_sqrtf(d2.z); d.w = fast_sqrtf(d2.w);
                d += DELTA;
                v4f inv;
                inv.x = fast_rcpf(d.x); inv.y = fast_rcpf(d.y);
                inv.z = fast_rcpf(d.z); inv.w = fast_rcpf(d.w);
                v4f inv2 = inv * inv;
                v4f inv6 = inv2 * inv2 * inv2;
                e1 = __builtin_elementwise_fma(lw, inv, e1);
                v1 = __builtin_elementwise_fma(inv6, inv6 - 1.0f, v1);
            }
        }

        double e = (double)(qp0 * ((e0.x + e0.y) + (e0.z + e0.w)))
                 + (double)(qp1 * ((e1.x + e1.y) + (e1.z + e1.w)));
        double v = (double)((v0.x + v0.y) + (v0.z + v0.w))
                 + (double)((v1.x + v1.y) + (v1.z + v1.w));
        #pragma unroll
        for (int off = 32; off > 0; off >>= 1) {
            e += __shfl_down(e, off, 64);
            v += __shfl_down(v, off, 64);
        }
        if (lane == 0) { sred[w][0] = e; sred[w][1] = v; }
        __syncthreads();
        if (tid == 0) {
            partials[2 * blk]     = sred[0][0] + sred[1][0] + sred[2][0] + sred[3][0];
            partials[2 * blk + 1] = sred[0][1] + sred[1][1] + sred[2][1] + sred[3][1];
        }
    } else {
        // ---------------- masked MSE / mreg partials ----------------
        const int idx = blk - NBINDBLK;          // [0,8)
        const int i   = idx * 256 + tid;         // [0, B*NL)
        float mk = mask[i];
        float a0 = pred_noise[3*i+0] - tgt_coords[3*i+0];
        float a1 = pred_noise[3*i+1] - tgt_coords[3*i+1];
        float a2 = pred_noise[3*i+2] - tgt_coords[3*i+2];
        double de = (double)mk * ((double)a0*a0 + (double)a1*a1 + (double)a2*a2);
        float s0 = scaf_coords[3*i+0] - tgt_coords[3*i+0];
        float s1 = scaf_coords[3*i+1] - tgt_coords[3*i+1];
        float s2 = scaf_coords[3*i+2] - tgt_coords[3*i+2];
        double mr = (double)mk * ((double)s0*s0 + (double)s1*s1 + (double)s2*s2);
        double ms = (double)mk;
        #pragma unroll
        for (int off = 32; off > 0; off >>= 1) {
            de += __shfl_down(de, off, 64);
            mr += __shfl_down(mr, off, 64);
            ms += __shfl_down(ms, off, 64);
        }
        if (lane == 0) { sred[w][0] = de; sred[w][1] = mr; sred[w][2] = ms; }
        __syncthreads();
        if (tid == 0) {
            partials[2*NBINDBLK + idx*3 + 0] = sred[0][0]+sred[1][0]+sred[2][0]+sred[3][0];
            partials[2*NBINDBLK + idx*3 + 1] = sred[0][1]+sred[1][1]+sred[2][1]+sred[3][1];
            partials[2*NBINDBLK + idx*3 + 2] = sred[0][2]+sred[1][2]+sred[2][2]+sred[3][2];
        }
    }
}

// ---------------------------------------------------------------------------
// Kernel 2: finalize — reduce all partials, write scalar loss.
// ---------------------------------------------------------------------------
__global__ __launch_bounds__(256) void finalize_kernel(
    const double* __restrict__ partials,
    float* __restrict__ out)
{
    const int tid = threadIdx.x;
    const int lane = tid & 63, w = tid >> 6;
    double el = 0.0, vd = 0.0;
    for (int i = tid; i < NBINDBLK; i += 256) {
        el += partials[2*i];
        vd += partials[2*i + 1];
    }
    double de = 0.0, mr = 0.0, ms = 0.0;
    if (tid < NMSE) {
        de = partials[2*NBINDBLK + tid*3 + 0];
        mr = partials[2*NBINDBLK + tid*3 + 1];
        ms = partials[2*NBINDBLK + tid*3 + 2];
    }
    #pragma unroll
    for (int off = 32; off > 0; off >>= 1) {
        el += __shfl_down(el, off, 64);
        vd += __shfl_down(vd, off, 64);
        de += __shfl_down(de, off, 64);
        mr += __shfl_down(mr, off, 64);
        ms += __shfl_down(ms, off, 64);
    }
    __shared__ double s[4][5];
    if (lane == 0) { s[w][0]=el; s[w][1]=vd; s[w][2]=de; s[w][3]=mr; s[w][4]=ms; }
    __syncthreads();
    if (tid == 0) {
        el = s[0][0]+s[1][0]+s[2][0]+s[3][0];
        vd = s[0][1]+s[1][1]+s[2][1]+s[3][1];
        de = s[0][2]+s[1][2]+s[2][2]+s[3][2];
        mr = s[0][3]+s[1][3]+s[2][3]+s[3][3];
        ms = s[0][4]+s[1][4]+s[2][4]+s[3][4];
        double loss_bind = (el + vd) / (double)B;
        double loss = de / ms + loss_bind + 0.1 * (mr / ms);
        out[0] = (float)loss;
    }
}

// ---------------------------------------------------------------------------
extern "C" void kernel_launch(void* const* d_in, const int* in_sizes, int n_in,
                              void* d_out, int out_size, void* d_ws, size_t ws_size,
                              hipStream_t stream)
{
    const float* pred_noise  = (const float*)d_in[0];
    const float* tgt_coords  = (const float*)d_in[1];
    const float* scaf_coords = (const float*)d_in[2];
    const float* tc2         = (const float*)d_in[3];
    const float* lig_feat    = (const float*)d_in[4];
    const float* mask        = (const float*)d_in[5];
    const float* prot_coords = (const float*)d_in[6];
    const float* prot_feat   = (const float*)d_in[7];
    const float* lig_tab     = (const float*)d_in[8];
    const float* prot_tab    = (const float*)d_in[9];
    float* out = (float*)d_out;

    double* partials = (double*)d_ws;   // 2*1024 + 24 doubles = ~16.6 KB

    pair_mse_kernel<<<NBINDBLK + NMSE, 256, 0, stream>>>(
        prot_coords, prot_feat, tc2, lig_feat, lig_tab, prot_tab,
        pred_noise, tgt_coords, scaf_coords, mask, partials);
    finalize_kernel<<<1, 256, 0, stream>>>(partials, out);
}